// Round 2
// baseline (328.092 us; speedup 1.0000x reference)
//
#include <hip/hip_runtime.h>

typedef _Float16 half8 __attribute__((ext_vector_type(8)));
typedef float f32x4 __attribute__((ext_vector_type(4)));

#define HW 16384
#define FDIM 256
#define DDIM 128

union H8 { half8 v; uint4 q; _Float16 h[8]; };
union H4 { uint2 q; _Float16 h[4]; };

// ---------------- prep: q projection (f32, exact) + MFMA-fragment pre-layout ----------------
__global__ __launch_bounds__(256) void prep_kernel(
    const float* __restrict__ proto, const float* __restrict__ Wk,
    const float* __restrict__ Wq, const float* __restrict__ bq,
    float* __restrict__ protos_out, _Float16* __restrict__ Wkf,
    _Float16* __restrict__ qf)
{
  const int bid = blockIdx.x, t = threadIdx.x;
  if (bid < 96) {
    const int b = bid / 6, c = bid % 6;
    __shared__ float protoS[10 * FDIM];
    const float* pbase = proto + (size_t)((b * 6 + c) * 10) * FDIM;
#pragma unroll
    for (int i = 0; i < 10; ++i) protoS[t + 256 * i] = pbase[t + 256 * i];
    __syncthreads();
#pragma unroll
    for (int i = 0; i < 5; ++i) {
      const int oid = t + 256 * i;               // 1280 outputs: (p, d)
      const int p = oid >> 7, d = oid & 127;
      const float* wq = Wq + (size_t)(c * DDIM + d) * FDIM;
      float acc = bq[c * DDIM + d];
      for (int f = 0; f < FDIM; ++f) acc += wq[f] * protoS[p * FDIM + f];
      protos_out[((b * 6 + c) * 10 + p) * DDIM + d] = acc;
      // qf[b][cpt][ks2][lane][j]: cp = cpt*16 + (l&15), d = ks2*32 + (l>>4)*8 + j
      const int cp = c * 10 + p;
      const int cpt = cp >> 4, lr = cp & 15, ks2 = d >> 5, lg = (d >> 3) & 3, j = d & 7;
      qf[((((b * 4 + cpt) * 4 + ks2) * 64) + lg * 16 + lr) * 8 + j] = (_Float16)acc;
    }
    if (c == 5) {  // zero the cp = 60..63 padding rows for this b
#pragma unroll
      for (int i = 0; i < 2; ++i) {
        const int zid = t + 256 * i;
        const int cp = 60 + (zid >> 7), d = zid & 127;
        const int cpt = cp >> 4, lr = cp & 15, ks2 = d >> 5, lg = (d >> 3) & 3, j = d & 7;
        qf[((((b * 4 + cpt) * 4 + ks2) * 64) + lg * 16 + lr) * 8 + j] = (_Float16)0.f;
      }
    }
  } else {
    // Wkf[mt][ks][lane][j]: d = mt*16 + (l&15), f = ks*32 + (l>>4)*8 + j
#pragma unroll
    for (int ii = 0; ii < 16; ++ii) {
      const int fl = t + 256 * ii;               // 4096 fragment-lanes
      const int mt = fl >> 9, ks = (fl >> 6) & 7, l = fl & 63;
      const int d = mt * 16 + (l & 15), f0 = ks * 32 + ((l >> 4) << 3);
      H8 h;
#pragma unroll
      for (int j = 0; j < 8; ++j) h.h[j] = (_Float16)Wk[d * FDIM + f0 + j];
      *reinterpret_cast<uint4*>(Wkf + (size_t)fl * 8) = h.q;
    }
  }
}

// ---------------- fused: key GEMM -> sim GEMM -> softmax-max -> weighted assp ----------------
// 32-pixel tile per block (R1 post-mortem: 50KB LDS capped occupancy at 22% -> latency-bound)
#define XB_OFF 0        // _Float16 X[32 pix][256 f], XOR-swizzled rows (16384 B)
#define KB_OFF 16384    // _Float16 K[32 pix][128 d], XOR-swizzled rows (8192 B)
#define WM_OFF 24576    // float wmax[32] (128 B)
#define BKS_OFF 24704   // float bk[128] (512 B)
#define SMEM_BYTES 25216

__global__ __launch_bounds__(256, 5) void fused_kernel(
    const float* __restrict__ assp, const float* __restrict__ bk,
    const _Float16* __restrict__ Wkf, const _Float16* __restrict__ qf,
    float* __restrict__ out)
{
  __shared__ __align__(16) char smem[SMEM_BYTES];
  const int t = threadIdx.x;
  const int b = blockIdx.x >> 9;
  const int tile = blockIdx.x & 511;
  const int pix = t & 31, cg = t >> 5;          // staging role: 8 channel-groups of 32
  const int w = t >> 6, l = t & 63, l4 = l >> 4, lr = l & 15;  // MFMA role
  const size_t gbase = (size_t)b * FDIM * HW + (size_t)tile * 32 + pix;

  if (t < 128) ((float*)(smem + BKS_OFF))[t] = bk[t];

  // ---- stage: 32 f32 assp values per thread stay in registers; f16 copy to LDS (transposed) ----
  float xv[32];
#pragma unroll
  for (int i = 0; i < 32; ++i) xv[i] = assp[gbase + (size_t)(cg * 32 + i) * HW];

#pragma unroll
  for (int g = 0; g < 4; ++g) {
    H8 h;
#pragma unroll
    for (int j = 0; j < 8; ++j) h.h[j] = (_Float16)xv[g * 8 + j];
    const int colb = (cg * 32 + g * 8) * 2;
    *reinterpret_cast<uint4*>(smem + XB_OFF + pix * 512 + (colb ^ ((pix & 7) << 4))) = h.q;
  }
  __syncthreads();

  // ---- GEMM1: key[d in w*32..+32][32 pix] = Wk x X ----
  f32x4 acc[2][2];
#pragma unroll
  for (int mt = 0; mt < 2; ++mt)
#pragma unroll
    for (int nt = 0; nt < 2; ++nt) acc[mt][nt] = (f32x4){0.f, 0.f, 0.f, 0.f};

#pragma unroll
  for (int ks = 0; ks < 8; ++ks) {
    const half8 a0 = *reinterpret_cast<const half8*>(Wkf + ((size_t)((w * 2 + 0) * 8 + ks) * 64 + l) * 8);
    const half8 a1 = *reinterpret_cast<const half8*>(Wkf + ((size_t)((w * 2 + 1) * 8 + ks) * 64 + l) * 8);
#pragma unroll
    for (int nt = 0; nt < 2; ++nt) {
      const int row = nt * 16 + lr;
      const half8 bb = *reinterpret_cast<const half8*>(
          smem + XB_OFF + row * 512 + ((ks * 64 + l4 * 16) ^ ((row & 7) << 4)));
      acc[0][nt] = __builtin_amdgcn_mfma_f32_16x16x32_f16(a0, bb, acc[0][nt], 0, 0, 0);
      acc[1][nt] = __builtin_amdgcn_mfma_f32_16x16x32_f16(a1, bb, acc[1][nt], 0, 0, 0);
    }
  }

  // ---- +bk, f16-ify, K tile to LDS: K[pix][d] ----
  const float* bks = (const float*)(smem + BKS_OFF);
#pragma unroll
  for (int mt = 0; mt < 2; ++mt) {
    const int d0 = w * 32 + mt * 16 + l4 * 4;   // D rows: m = (l>>4)*4 + reg
    const float b0 = bks[d0], b1 = bks[d0 + 1], b2 = bks[d0 + 2], b3 = bks[d0 + 3];
#pragma unroll
    for (int nt = 0; nt < 2; ++nt) {
      H4 h;
      h.h[0] = (_Float16)(acc[mt][nt][0] + b0);
      h.h[1] = (_Float16)(acc[mt][nt][1] + b1);
      h.h[2] = (_Float16)(acc[mt][nt][2] + b2);
      h.h[3] = (_Float16)(acc[mt][nt][3] + b3);
      const int prow = nt * 16 + lr;            // D cols: n = l&15
      *reinterpret_cast<uint2*>(smem + KB_OFF + prow * 256 + ((d0 * 2) ^ ((prow & 7) << 4))) = h.q;
    }
  }
  __syncthreads();

  // ---- GEMM2: sim[cp tile w][32 pix] = q x key ----
  f32x4 acc2[2];
#pragma unroll
  for (int nt = 0; nt < 2; ++nt) acc2[nt] = (f32x4){0.f, 0.f, 0.f, 0.f};
#pragma unroll
  for (int ks2 = 0; ks2 < 4; ++ks2) {
    const half8 a2 = *reinterpret_cast<const half8*>(qf + ((size_t)((b * 4 + w) * 4 + ks2) * 64 + l) * 8);
#pragma unroll
    for (int nt = 0; nt < 2; ++nt) {
      const int row = nt * 16 + lr;
      const half8 bb = *reinterpret_cast<const half8*>(
          smem + KB_OFF + row * 256 + ((ks2 * 64 + l4 * 16) ^ ((row & 7) << 4)));
      acc2[nt] = __builtin_amdgcn_mfma_f32_16x16x32_f16(a2, bb, acc2[nt], 0, 0, 0);
    }
  }

  // ---- scatter sim[pix][cp] (f32, stride 65; overlays dead X tile after the sync above) ----
  float* sim = (float*)(smem + XB_OFF);
#pragma unroll
  for (int nt = 0; nt < 2; ++nt) {
    const int spix = nt * 16 + lr;
#pragma unroll
    for (int r = 0; r < 4; ++r) sim[spix * 65 + (w * 16 + l4 * 4 + r)] = acc2[nt][r];
  }
  __syncthreads();

  // ---- wmax[pix] = max softmax = 1 / sum_cp exp(sim - max); only cp < 60 are real ----
  if (t < 128) {
    const int spix = t >> 2, rq = t & 3;        // 4 threads per pixel, 15 cps each
    const float* srow = sim + spix * 65 + rq * 15;
    float m = -1e30f;
#pragma unroll
    for (int i = 0; i < 15; ++i) m = fmaxf(m, srow[i]);
    m = fmaxf(m, __shfl_xor(m, 1));
    m = fmaxf(m, __shfl_xor(m, 2));
    float s = 0.f;
#pragma unroll
    for (int i = 0; i < 15; ++i) s += expf(srow[i] - m);
    s += __shfl_xor(s, 1);
    s += __shfl_xor(s, 2);
    if (rq == 0) ((float*)(smem + WM_OFF))[spix] = 1.0f / s;
  }
  __syncthreads();

  // ---- output: exact f32 assp (from regs) * wmax ----
  const float wm = ((float*)(smem + WM_OFF))[pix];
#pragma unroll
  for (int i = 0; i < 32; ++i) out[gbase + (size_t)(cg * 32 + i) * HW] = xv[i] * wm;
}

extern "C" void kernel_launch(void* const* d_in, const int* in_sizes, int n_in,
                              void* d_out, int out_size, void* d_ws, size_t ws_size,
                              hipStream_t stream) {
  const float* assp  = (const float*)d_in[0];
  const float* proto = (const float*)d_in[1];
  const float* Wk    = (const float*)d_in[2];
  const float* bk    = (const float*)d_in[3];
  const float* Wq    = (const float*)d_in[4];
  const float* bq    = (const float*)d_in[5];
  float* out = (float*)d_out;
  float* protos_out = out + (size_t)16 * FDIM * HW;   // 67,108,864

  _Float16* Wkf = (_Float16*)d_ws;                    // 32768 halves
  _Float16* qf  = Wkf + 32768;                        // 131072 halves

  prep_kernel<<<97, 256, 0, stream>>>(proto, Wk, Wq, bq, protos_out, Wkf, qf);
  fused_kernel<<<16 * 512, 256, 0, stream>>>(assp, bk, Wkf, qf, out);
}

// Round 3
// 147.769 us; speedup vs baseline: 2.2203x; 2.2203x over previous
//
#include <hip/hip_runtime.h>

typedef _Float16 half8 __attribute__((ext_vector_type(8)));
typedef float f32x4 __attribute__((ext_vector_type(4)));

#define HW 16384
#define FDIM 256
#define DDIM 128

union H8 { half8 v; uint4 q; _Float16 h[8]; };
union H4 { uint2 q; _Float16 h[4]; };

// ---------------- prep: q projection (f32, exact) + MFMA-fragment pre-layout ----------------
__global__ __launch_bounds__(256) void prep_kernel(
    const float* __restrict__ proto, const float* __restrict__ Wk,
    const float* __restrict__ Wq, const float* __restrict__ bq,
    float* __restrict__ protos_out, _Float16* __restrict__ Wkf,
    _Float16* __restrict__ qf)
{
  const int bid = blockIdx.x, t = threadIdx.x;
  if (bid < 96) {
    const int b = bid / 6, c = bid % 6;
    __shared__ float protoS[10 * FDIM];
    const float* pbase = proto + (size_t)((b * 6 + c) * 10) * FDIM;
#pragma unroll
    for (int i = 0; i < 10; ++i) protoS[t + 256 * i] = pbase[t + 256 * i];
    __syncthreads();
#pragma unroll
    for (int i = 0; i < 5; ++i) {
      const int oid = t + 256 * i;               // 1280 outputs: (p, d)
      const int p = oid >> 7, d = oid & 127;
      const float* wq = Wq + (size_t)(c * DDIM + d) * FDIM;
      float acc = bq[c * DDIM + d];
      for (int f = 0; f < FDIM; ++f) acc += wq[f] * protoS[p * FDIM + f];
      protos_out[((b * 6 + c) * 10 + p) * DDIM + d] = acc;
      // qf[b][cpt][ks2][lane][j]: cp = cpt*16 + (l&15), d = ks2*32 + (l>>4)*8 + j
      const int cp = c * 10 + p;
      const int cpt = cp >> 4, lr = cp & 15, ks2 = d >> 5, lg = (d >> 3) & 3, j = d & 7;
      qf[((((b * 4 + cpt) * 4 + ks2) * 64) + lg * 16 + lr) * 8 + j] = (_Float16)acc;
    }
    if (c == 5) {  // zero the cp = 60..63 padding rows for this b
#pragma unroll
      for (int i = 0; i < 2; ++i) {
        const int zid = t + 256 * i;
        const int cp = 60 + (zid >> 7), d = zid & 127;
        const int cpt = cp >> 4, lr = cp & 15, ks2 = d >> 5, lg = (d >> 3) & 3, j = d & 7;
        qf[((((b * 4 + cpt) * 4 + ks2) * 64) + lg * 16 + lr) * 8 + j] = (_Float16)0.f;
      }
    }
  } else {
    // Wkf[mt][ks][lane][j]: d = mt*16 + (l&15), f = ks*32 + (l>>4)*8 + j
#pragma unroll
    for (int ii = 0; ii < 16; ++ii) {
      const int fl = t + 256 * ii;               // 4096 fragment-lanes
      const int mt = fl >> 9, ks = (fl >> 6) & 7, l = fl & 63;
      const int d = mt * 16 + (l & 15), f0 = ks * 32 + ((l >> 4) << 3);
      H8 h;
#pragma unroll
      for (int j = 0; j < 8; ++j) h.h[j] = (_Float16)Wk[d * FDIM + f0 + j];
      *reinterpret_cast<uint4*>(Wkf + (size_t)fl * 8) = h.q;
    }
  }
}

// ---------------- fused: key GEMM -> sim GEMM -> softmax-max -> weighted assp ----------------
// 32-pixel tile, NO xv registers (R2 post-mortem: launch_bounds squeeze spilled xv -> 600MB
// scratch traffic). Output re-reads the f16 X tile from LDS instead; sim overlays K (not X).
#define XB_OFF 0        // _Float16 X[32 pix][256 f], XOR-swizzled rows (16384 B) — alive to the end
#define SIMK_OFF 16384  // union: _Float16 K[32][128] swizzled (8192 B) then f32 sim[32][65] (8320 B)
#define WM_OFF 24704    // float wmax[32] (128 B)
#define BKS_OFF 24832   // float bk[128] (512 B)
#define SMEM_BYTES 25344

__global__ __launch_bounds__(256, 8) void fused_kernel(
    const float* __restrict__ assp, const float* __restrict__ bk,
    const _Float16* __restrict__ Wkf, const _Float16* __restrict__ qf,
    float* __restrict__ out)
{
  __shared__ __align__(16) char smem[SMEM_BYTES];
  const int t = threadIdx.x;
  const int b = blockIdx.x >> 9;
  const int tile = blockIdx.x & 511;
  const int pix = t & 31, cg = t >> 5;          // staging role: 8 channel-groups of 32
  const int w = t >> 6, l = t & 63, l4 = l >> 4, lr = l & 15;  // MFMA role
  const size_t gbase = (size_t)b * FDIM * HW + (size_t)tile * 32 + pix;

  if (t < 128) ((float*)(smem + BKS_OFF))[t] = bk[t];

  // ---- stage: load 32 f32 assp values, convert to f16 into LDS (transposed, swizzled) ----
#pragma unroll
  for (int g = 0; g < 4; ++g) {
    float x[8];
#pragma unroll
    for (int j = 0; j < 8; ++j) x[j] = assp[gbase + (size_t)(cg * 32 + g * 8 + j) * HW];
    H8 h;
#pragma unroll
    for (int j = 0; j < 8; ++j) h.h[j] = (_Float16)x[j];
    const int colb = (cg * 32 + g * 8) * 2;
    *reinterpret_cast<uint4*>(smem + XB_OFF + pix * 512 + (colb ^ ((pix & 7) << 4))) = h.q;
  }
  __syncthreads();

  // ---- GEMM1: key[d in w*32..+32][32 pix] = Wk x X ----
  f32x4 acc[2][2];
#pragma unroll
  for (int mt = 0; mt < 2; ++mt)
#pragma unroll
    for (int nt = 0; nt < 2; ++nt) acc[mt][nt] = (f32x4){0.f, 0.f, 0.f, 0.f};

#pragma unroll
  for (int ks = 0; ks < 8; ++ks) {
    const half8 a0 = *reinterpret_cast<const half8*>(Wkf + ((size_t)((w * 2 + 0) * 8 + ks) * 64 + l) * 8);
    const half8 a1 = *reinterpret_cast<const half8*>(Wkf + ((size_t)((w * 2 + 1) * 8 + ks) * 64 + l) * 8);
#pragma unroll
    for (int nt = 0; nt < 2; ++nt) {
      const int row = nt * 16 + lr;
      const half8 bb = *reinterpret_cast<const half8*>(
          smem + XB_OFF + row * 512 + ((ks * 64 + l4 * 16) ^ ((row & 7) << 4)));
      acc[0][nt] = __builtin_amdgcn_mfma_f32_16x16x32_f16(a0, bb, acc[0][nt], 0, 0, 0);
      acc[1][nt] = __builtin_amdgcn_mfma_f32_16x16x32_f16(a1, bb, acc[1][nt], 0, 0, 0);
    }
  }

  // ---- +bk, f16-ify, K tile to LDS: K[pix][d] ----
  const float* bks = (const float*)(smem + BKS_OFF);
#pragma unroll
  for (int mt = 0; mt < 2; ++mt) {
    const int d0 = w * 32 + mt * 16 + l4 * 4;   // D rows: m = (l>>4)*4 + reg
    const float b0 = bks[d0], b1 = bks[d0 + 1], b2 = bks[d0 + 2], b3 = bks[d0 + 3];
#pragma unroll
    for (int nt = 0; nt < 2; ++nt) {
      H4 h;
      h.h[0] = (_Float16)(acc[mt][nt][0] + b0);
      h.h[1] = (_Float16)(acc[mt][nt][1] + b1);
      h.h[2] = (_Float16)(acc[mt][nt][2] + b2);
      h.h[3] = (_Float16)(acc[mt][nt][3] + b3);
      const int prow = nt * 16 + lr;            // D cols: n = l&15
      *reinterpret_cast<uint2*>(smem + SIMK_OFF + prow * 256 + ((d0 * 2) ^ ((prow & 7) << 4))) = h.q;
    }
  }
  __syncthreads();

  // ---- GEMM2: sim[cp tile w][32 pix] = q x key ----
  f32x4 acc2[2];
#pragma unroll
  for (int nt = 0; nt < 2; ++nt) acc2[nt] = (f32x4){0.f, 0.f, 0.f, 0.f};
#pragma unroll
  for (int ks2 = 0; ks2 < 4; ++ks2) {
    const half8 a2 = *reinterpret_cast<const half8*>(qf + ((size_t)((b * 4 + w) * 4 + ks2) * 64 + l) * 8);
#pragma unroll
    for (int nt = 0; nt < 2; ++nt) {
      const int row = nt * 16 + lr;
      const half8 bb = *reinterpret_cast<const half8*>(
          smem + SIMK_OFF + row * 256 + ((ks2 * 64 + l4 * 16) ^ ((row & 7) << 4)));
      acc2[nt] = __builtin_amdgcn_mfma_f32_16x16x32_f16(a2, bb, acc2[nt], 0, 0, 0);
    }
  }
  __syncthreads();   // all waves done reading K before sim overlays it

  // ---- scatter sim[pix][cp] (f32, stride 65; overlays dead K tile) ----
  float* sim = (float*)(smem + SIMK_OFF);
#pragma unroll
  for (int nt = 0; nt < 2; ++nt) {
    const int spix = nt * 16 + lr;
#pragma unroll
    for (int r = 0; r < 4; ++r) sim[spix * 65 + (w * 16 + l4 * 4 + r)] = acc2[nt][r];
  }
  __syncthreads();

  // ---- wmax[pix] = max softmax = 1 / sum_cp exp(sim - max); only cp < 60 are real ----
  if (t < 128) {
    const int spix = t >> 2, rq = t & 3;        // 4 threads per pixel, 15 cps each
    const float* srow = sim + spix * 65 + rq * 15;
    float m = -1e30f;
#pragma unroll
    for (int i = 0; i < 15; ++i) m = fmaxf(m, srow[i]);
    m = fmaxf(m, __shfl_xor(m, 1));
    m = fmaxf(m, __shfl_xor(m, 2));
    float s = 0.f;
#pragma unroll
    for (int i = 0; i < 15; ++i) s += expf(srow[i] - m);
    s += __shfl_xor(s, 1);
    s += __shfl_xor(s, 2);
    if (rq == 0) ((float*)(smem + WM_OFF))[spix] = 1.0f / s;
  }
  __syncthreads();

  // ---- output: read back own f16 X from LDS, multiply by wmax, nontemporal f32 store ----
  const float wm = ((float*)(smem + WM_OFF))[pix];
#pragma unroll
  for (int g = 0; g < 4; ++g) {
    H8 h;
    const int colb = (cg * 32 + g * 8) * 2;
    h.q = *reinterpret_cast<const uint4*>(smem + XB_OFF + pix * 512 + (colb ^ ((pix & 7) << 4)));
#pragma unroll
    for (int j = 0; j < 8; ++j)
      __builtin_nontemporal_store((float)h.h[j] * wm,
                                  &out[gbase + (size_t)(cg * 32 + g * 8 + j) * HW]);
  }
}

extern "C" void kernel_launch(void* const* d_in, const int* in_sizes, int n_in,
                              void* d_out, int out_size, void* d_ws, size_t ws_size,
                              hipStream_t stream) {
  const float* assp  = (const float*)d_in[0];
  const float* proto = (const float*)d_in[1];
  const float* Wk    = (const float*)d_in[2];
  const float* bk    = (const float*)d_in[3];
  const float* Wq    = (const float*)d_in[4];
  const float* bq    = (const float*)d_in[5];
  float* out = (float*)d_out;
  float* protos_out = out + (size_t)16 * FDIM * HW;   // 67,108,864

  _Float16* Wkf = (_Float16*)d_ws;                    // 32768 halves
  _Float16* qf  = Wkf + 32768;                        // 131072 halves

  prep_kernel<<<97, 256, 0, stream>>>(proto, Wk, Wq, bq, protos_out, Wkf, qf);
  fused_kernel<<<16 * 512, 256, 0, stream>>>(assp, bk, Wkf, qf, out);
}